// Round 7
// baseline (134.726 us; speedup 1.0000x reference)
//
#include <hip/hip_runtime.h>
#include <hip/hip_bf16.h>
#include <math.h>

// LargeMarginLoss: loss = log1p(neg_sum / pos_sum) over e = exp(30*(cos_sim - 0.2))
// B=8192, D=512, labels in [0,100). Output: 1 float32 scalar.
//
// norm (fp32 norms -> bf16 rows); fused 256^2 MFMA GEMM-loss with a 4-deep
// circular LDS pipeline (BK=32, prefetch 3 K-tiles ahead, counted vmcnt(8)),
// template phase order (reads+stage BEFORE barrier), XCD-contiguous
// triangular grid, exp+mask+reduce epilogue, last-block finalize.

#define BDIM 8192
#define DDIM 512
#define MARGIN 0.2f
#define SCALE 30.0f

#define BT 256               // output tile (BM=BN)
#define BK 32                // K-step
#define NKT (DDIM / BK)      // 16 K-tiles
#define NT (BDIM / BT)       // 32
#define NBLK (NT * (NT + 1) / 2)   // 528 upper-tri tiles (= 8 XCDs * 66)

typedef __hip_bfloat16 bf16;
using f32x4  = __attribute__((ext_vector_type(4))) float;
using bf16x8 = __attribute__((ext_vector_type(8))) short;
using us8    = __attribute__((ext_vector_type(8))) unsigned short;

#define GLOAD_LDS16(gp, lp)                                                    \
    __builtin_amdgcn_global_load_lds(                                          \
        (const __attribute__((address_space(1))) unsigned int*)(gp),           \
        (__attribute__((address_space(3))) unsigned int*)(lp), 16, 0, 0)

__device__ __forceinline__ unsigned short f2bf(float x) {
    union { bf16 h; unsigned short u; } c;
    c.h = __float2bfloat16(x);
    return c.u;
}

// ---------------------------------------------------------------------------
// Kernel 1: row L2-normalize, emit bf16. One wave per row; block 0 thread 0
// zero-inits the accumulators + completion counter.
__global__ __launch_bounds__(256)
void norm_rows_kernel(const float* __restrict__ emb, bf16* __restrict__ nout,
                      double* __restrict__ accum, unsigned* __restrict__ ctr) {
    if (blockIdx.x == 0 && threadIdx.x == 0) {
        accum[0] = 0.0; accum[1] = 0.0; *ctr = 0u;
    }
    const int row  = blockIdx.x * 4 + (threadIdx.x >> 6);
    const int lane = threadIdx.x & 63;
    const float4* src = (const float4*)(emb + (size_t)row * DDIM) + lane * 2;
    const float4 a = src[0];
    const float4 b = src[1];
    float ss = a.x * a.x + a.y * a.y + a.z * a.z + a.w * a.w
             + b.x * b.x + b.y * b.y + b.z * b.z + b.w * b.w;
    #pragma unroll
    for (int off = 1; off < 64; off <<= 1) ss += __shfl_xor(ss, off, 64);
    const float inv = 1.0f / fmaxf(sqrtf(ss), 1e-8f);
    float v[8] = { a.x, a.y, a.z, a.w, b.x, b.y, b.z, b.w };
    us8 o;
    #pragma unroll
    for (int i = 0; i < 8; ++i) o[i] = f2bf(v[i] * inv);
    *((us8*)(nout + (size_t)row * DDIM) + lane) = o;
}

// ---------------------------------------------------------------------------
// Kernel 2: 256^2-tile fused GEMM-loss, 4-deep circular buffer.
//   8 waves (2M x 4N), per-wave 128x64 output = 8x4 frags of 16x16x32.
//   LDS: As/Bs[4 bufs][256][32] bf16 = 128 KB. Swizzle (both sides):
//   physical chunk16 = logical chunk16 ^ ((row>>1)&3). gload_lds writes
//   linearly -> swizzle pre-applied on the GLOBAL source column.
//   Per K-tile: 2 phases x {ds_read, stage half-tiles of tile t+3, barrier,
//   lgkmcnt(0), 16 MFMA}; vmcnt(8) once per K-tile (3 tiles in flight).
__global__ __launch_bounds__(512, 2)
void gemm_loss_kernel(const bf16* __restrict__ nmat,
                      const int* __restrict__ labels,
                      double* __restrict__ accum, unsigned* __restrict__ ctr,
                      float* __restrict__ out) {
    // --- XCD-contiguous triangular decode: hw -> l -> (bi, bj), bi <= bj ---
    const int hw = blockIdx.x;
    const int l = (hw & 7) * (NBLK / 8) + (hw >> 3);   // XCD x gets 66 contiguous
    auto tri = [](int b) { return ((65 - b) * b) >> 1; };
    int bi = (int)((65.0 - sqrt(4225.0 - 8.0 * (double)l)) * 0.5);
    bi = bi < 0 ? 0 : (bi > 31 ? 31 : bi);
    while (bi > 0 && tri(bi) > l) --bi;
    while (tri(bi + 1) <= l) ++bi;
    const int bj = bi + (l - tri(bi));

    __shared__ alignas(16) short As[4][BT * BK];   // 4 x 16 KB
    __shared__ alignas(16) short Bs[4][BT * BK];   // 4 x 16 KB
    __shared__ int lr[BT], lc[BT];
    __shared__ double red[16];

    const int tix = threadIdx.x, wid = tix >> 6, lane = tix & 63;
    if (tix < 256) lr[tix] = labels[bi * BT + tix];
    else           lc[tix - 256] = labels[bj * BT + (tix - 256)];

    const int wm = wid >> 2;          // 0..1  (M half)
    const int wn = wid & 3;           // 0..3  (N quarter)

    // --- staging: half-tile = [128 rows][32 cols] = 8 KB = 1 load/thread.
    // Thread (wid,lane): row = h*128 + wid*16 + (lane>>2); LDS chunk lane&3
    // holds global chunk (lane&3)^((row>>1)&3) = (lane&3)^((lane>>3)&3).
    const int srow = wid * 16 + (lane >> 2);
    const int scol = ((lane & 3) ^ ((lane >> 3) & 3)) * 8;  // pre-swizzled col
    const bf16* gA = nmat + (size_t)(bi * BT + srow) * DDIM + scol;
    const bf16* gB = nmat + (size_t)(bj * BT + srow) * DDIM + scol;
    const int ldst = wid * 16 * BK;   // wave-uniform LDS offset within half

    #define STG_A(buf, kt, h)                                                  \
        GLOAD_LDS16(gA + (size_t)((h) * 128) * DDIM + (kt) * BK,               \
                    &As[buf][(h) * 128 * BK + ldst])
    #define STG_B(buf, kt, h)                                                  \
        GLOAD_LDS16(gB + (size_t)((h) * 128) * DDIM + (kt) * BK,               \
                    &Bs[buf][(h) * 128 * BK + ldst])

    // --- fragment reads: row = base + m*16 + (lane&15), k-chunk = lane>>4,
    // physical chunk = (lane>>4) ^ ((row>>1)&3) = (lane>>4) ^ ((lane>>1)&3).
    const int aoff  = (lane & 15) * BK + (((lane >> 4) ^ ((lane >> 1) & 3)) * 8);
    const int abase = wm * 128 * BK;
    const int bbase = wn * 64 * BK;

    f32x4 acc[8][4] = {};

    // --- prologue: stage tiles 0..2 (12 loads/thread), retire tile 0 ---
    #pragma unroll
    for (int tt = 0; tt < 3; ++tt) {
        STG_A(tt, tt, 0); STG_A(tt, tt, 1);
        STG_B(tt, tt, 0); STG_B(tt, tt, 1);
    }
    asm volatile("s_waitcnt vmcnt(8)" ::: "memory");
    __builtin_amdgcn_s_barrier();
    asm volatile("" ::: "memory");

    #pragma unroll
    for (int t = 0; t < NKT; ++t) {
        const int cur = t & 3, pre = (t + 3) & 3;
        bf16x8 a[4], b[4];
        // ---- phase 0: read A.m0-3 + B.all; stage A(t+3); bar; MFMA ----
        #pragma unroll
        for (int m = 0; m < 4; ++m)
            a[m] = *(const bf16x8*)&As[cur][abase + m * (16 * BK) + aoff];
        #pragma unroll
        for (int n = 0; n < 4; ++n)
            b[n] = *(const bf16x8*)&Bs[cur][bbase + n * (16 * BK) + aoff];
        if (t < NKT - 3) { STG_A(pre, t + 3, 0); STG_A(pre, t + 3, 1); }
        __builtin_amdgcn_s_barrier();
        asm volatile("s_waitcnt lgkmcnt(0)" ::: "memory");
        __builtin_amdgcn_sched_barrier(0);
        __builtin_amdgcn_s_setprio(1);
        #pragma unroll
        for (int m = 0; m < 4; ++m)
            #pragma unroll
            for (int n = 0; n < 4; ++n)
                acc[m][n] = __builtin_amdgcn_mfma_f32_16x16x32_bf16(
                    a[m], b[n], acc[m][n], 0, 0, 0);
        __builtin_amdgcn_s_setprio(0);
        // ---- phase 1: read A.m4-7 (B reused); stage B(t+3); vmcnt; bar ----
        #pragma unroll
        for (int m = 0; m < 4; ++m)
            a[m] = *(const bf16x8*)&As[cur][abase + (m + 4) * (16 * BK) + aoff];
        if (t < NKT - 3) { STG_B(pre, t + 3, 0); STG_B(pre, t + 3, 1); }
        // retire tile t+1 (leave t+2, t+3 = 8 loads in flight)
        if (t <= NKT - 4)      { asm volatile("s_waitcnt vmcnt(8)" ::: "memory"); }
        else if (t == NKT - 3) { asm volatile("s_waitcnt vmcnt(4)" ::: "memory"); }
        else if (t == NKT - 2) { asm volatile("s_waitcnt vmcnt(0)" ::: "memory"); }
        __builtin_amdgcn_s_barrier();
        asm volatile("s_waitcnt lgkmcnt(0)" ::: "memory");
        __builtin_amdgcn_sched_barrier(0);
        __builtin_amdgcn_s_setprio(1);
        #pragma unroll
        for (int m = 0; m < 4; ++m)
            #pragma unroll
            for (int n = 0; n < 4; ++n)
                acc[m + 4][n] = __builtin_amdgcn_mfma_f32_16x16x32_bf16(
                    a[m], b[n], acc[m + 4][n], 0, 0, 0);
        __builtin_amdgcn_s_setprio(0);
    }
    #undef STG_A
    #undef STG_B

    // --- epilogue: e = exp(SCALE*(sim - MARGIN)); masked accumulate ---
    // C/D layout: col = lane&15, row = (lane>>4)*4 + reg.
    float posf = 0.0f, negf = 0.0f;
    const int rbase = wm * 128 + (lane >> 4) * 4;
    const int cbase = wn * 64 + (lane & 15);
    #pragma unroll
    for (int m = 0; m < 8; ++m) {
        #pragma unroll
        for (int n = 0; n < 4; ++n) {
            const int ljv = lc[cbase + n * 16];
            #pragma unroll
            for (int r = 0; r < 4; ++r) {
                const float e = __expf(fmaf(acc[m][n][r], SCALE, -SCALE * MARGIN));
                if (lr[rbase + m * 16 + r] == ljv) posf += e; else negf += e;
            }
        }
    }

    double dp = (double)posf, dn = (double)negf;
    #pragma unroll
    for (int o = 32; o > 0; o >>= 1) {
        dp += __shfl_down(dp, o, 64);
        dn += __shfl_down(dn, o, 64);
    }
    if (lane == 0) { red[wid * 2] = dp; red[wid * 2 + 1] = dn; }
    __syncthreads();
    if (tix == 0) {
        const double w = (bi == bj) ? 1.0 : 2.0;
        double p = 0.0, q = 0.0;
        #pragma unroll
        for (int i = 0; i < 8; ++i) { p += red[2 * i]; q += red[2 * i + 1]; }
        atomicAdd(&accum[0], p * w);
        atomicAdd(&accum[1], q * w);
        __threadfence();
        unsigned prev = atomicAdd(ctr, 1u);
        if (prev == NBLK - 1) {
            __threadfence();
            double pp = atomicAdd(&accum[0], 0.0);
            double qq = atomicAdd(&accum[1], 0.0);
            out[0] = (float)log1p(qq / pp);
        }
    }
}

// ---------------------------------------------------------------------------
extern "C" void kernel_launch(void* const* d_in, const int* in_sizes, int n_in,
                              void* d_out, int out_size, void* d_ws, size_t ws_size,
                              hipStream_t stream) {
    const float* emb  = (const float*)d_in[0];
    const int* labels = (const int*)d_in[1];
    float* out        = (float*)d_out;

    double* accum = (double*)d_ws;                       // 2 doubles
    unsigned* ctr = (unsigned*)((char*)d_ws + 16);
    bf16* nmat    = (bf16*)((char*)d_ws + 256);          // 8 MB

    norm_rows_kernel<<<BDIM / 4, 256, 0, stream>>>(emb, nmat, accum, ctr);
    gemm_loss_kernel<<<NBLK, 512, 0, stream>>>(nmat, labels, accum, ctr, out);
}